// Round 1
// baseline (138.330 us; speedup 1.0000x reference)
//
#include <hip/hip_runtime.h>
#include <stdint.h>

// Problem constants
constexpr int Tn = 4, Bn = 8, Cn = 64, Hn = 128, Wn = 128;
constexpr int HsC = 64, WsC = 64;      // downsampled spatial
constexpr int Kn = 256;                // C * r^2
constexpr float DECAYF = 0.25f;

// ---------------------------------------------------------------------------
// Kernel 1: PixelUnshuffle + LIF scan (16 sequential steps), spikes -> uint8
// One thread handles 4 consecutive ws-sites of one (b, c, hs).
// Spike layout: sp[((t*Bn + b)*Kn + (c*4 + p)) * (Hs*Ws) + hs*Ws + ws]
// ---------------------------------------------------------------------------
__global__ __launch_bounds__(256) void lif_kernel(const float* __restrict__ x,
                                                  uint8_t* __restrict__ sp) {
    int g = blockIdx.x * 256 + threadIdx.x;   // 524288 threads total
    int wq = g & 15;          // ws quad index: ws0 = 4*wq
    int hs = (g >> 4) & 63;
    int c  = (g >> 10) & 63;
    int b  = g >> 16;         // 0..7

    float mem[4] = {0.f, 0.f, 0.f, 0.f};
    float spk[4] = {0.f, 0.f, 0.f, 0.f};

    #pragma unroll
    for (int t = 0; t < 4; ++t) {
        const float* xr_ = x + (((size_t)t * Bn + b) * Cn + c) * (Hn * Wn)
                             + (2 * hs) * Wn + 8 * wq;
        float4 r0a = *(const float4*)(xr_);
        float4 r0b = *(const float4*)(xr_ + 4);
        float4 r1a = *(const float4*)(xr_ + Wn);
        float4 r1b = *(const float4*)(xr_ + Wn + 4);
        float r0[8] = {r0a.x, r0a.y, r0a.z, r0a.w, r0b.x, r0b.y, r0b.z, r0b.w};
        float r1[8] = {r1a.x, r1a.y, r1a.z, r1a.w, r1b.x, r1b.y, r1b.z, r1b.w};

        uint8_t* spb = sp + (((size_t)t * Bn + b) * Kn + c * 4) * (HsC * WsC)
                          + hs * WsC + 4 * wq;
        #pragma unroll
        for (int p = 0; p < 4; ++p) {   // p = i*2 + j, time order within t
            int j = p & 1;
            uint32_t pack = 0;
            #pragma unroll
            for (int s = 0; s < 4; ++s) {
                float xi = (p < 2) ? r0[2 * s + j] : r1[2 * s + j];
                mem[s] = (mem[s] - spk[s]) * DECAYF + xi;
                float mc = fminf(fmaxf(mem[s], 0.f), 4.f);
                float sv = rintf(mc);           // round half-to-even == jnp.round
                spk[s] = sv * 0.25f;
                pack |= ((uint32_t)(int)sv) << (8 * s);
            }
            *(uint32_t*)(spb + (size_t)p * (HsC * WsC)) = pack;
        }
    }
}

// ---------------------------------------------------------------------------
// Kernel 2: 1x1 conv at LOW resolution (conv commutes with bilinear upsample)
// Per (t,b): y[c][px] = sum_k (0.25*w[c][k]) * sp_u8[k][px],  M=64 N=4096 K=256
// Block: 256 threads = 4 c-groups x 64 px-threads; thread: 16 c x 4 px.
// ---------------------------------------------------------------------------
__global__ __launch_bounds__(256) void conv_kernel(const uint8_t* __restrict__ sp,
                                                   const float* __restrict__ w,
                                                   float* __restrict__ y) {
    __shared__ float4 wl[4096];   // [c][kq] : 64 x 64 float4 = 64 KB

    int tid = threadIdx.x;
    const float4* w4 = (const float4*)w;
    #pragma unroll
    for (int it = 0; it < 16; ++it) {
        int idx = it * 256 + tid;
        float4 v = w4[idx];
        v.x *= 0.25f; v.y *= 0.25f; v.z *= 0.25f; v.w *= 0.25f;
        wl[idx] = v;
    }
    __syncthreads();

    int tb   = blockIdx.x >> 4;       // 0..31  (t*B + b)
    int tile = blockIdx.x & 15;       // pixel tile of 256
    int pxt  = tid & 63;
    int cg   = tid >> 6;              // 0..3
    int c0   = cg * 16;
    int px0  = tile * 256 + pxt * 4;

    const uint8_t* sb = sp + (size_t)tb * Kn * (HsC * WsC) + px0;

    float4 acc[16];
    #pragma unroll
    for (int i = 0; i < 16; ++i) acc[i] = make_float4(0.f, 0.f, 0.f, 0.f);

    for (int kq = 0; kq < 64; ++kq) {
        uint32_t sv[4];
        #pragma unroll
        for (int kk = 0; kk < 4; ++kk)
            sv[kk] = *(const uint32_t*)(sb + (size_t)(kq * 4 + kk) * (HsC * WsC));
        float4 xv[4];
        #pragma unroll
        for (int kk = 0; kk < 4; ++kk) {
            xv[kk].x = (float)(sv[kk] & 0xffu);
            xv[kk].y = (float)((sv[kk] >> 8) & 0xffu);
            xv[kk].z = (float)((sv[kk] >> 16) & 0xffu);
            xv[kk].w = (float)(sv[kk] >> 24);
        }
        #pragma unroll
        for (int ci = 0; ci < 16; ++ci) {
            float4 wv = wl[(c0 + ci) * 64 + kq];
            acc[ci].x += wv.x * xv[0].x + wv.y * xv[1].x + wv.z * xv[2].x + wv.w * xv[3].x;
            acc[ci].y += wv.x * xv[0].y + wv.y * xv[1].y + wv.z * xv[2].y + wv.w * xv[3].y;
            acc[ci].z += wv.x * xv[0].z + wv.y * xv[1].z + wv.z * xv[2].z + wv.w * xv[3].z;
            acc[ci].w += wv.x * xv[0].w + wv.y * xv[1].w + wv.z * xv[2].w + wv.w * xv[3].w;
        }
    }

    float* yb = y + (size_t)tb * Cn * (HsC * WsC) + px0;
    #pragma unroll
    for (int ci = 0; ci < 16; ++ci)
        *(float4*)(yb + (size_t)(c0 + ci) * (HsC * WsC)) = acc[ci];
}

// ---------------------------------------------------------------------------
// Kernel 3: bilinear 2x upsample (half-pixel centers, edge clamped)
// One thread computes a float4 (4 consecutive output cols) of one row.
// ---------------------------------------------------------------------------
__global__ __launch_bounds__(256) void upsample_kernel(const float* __restrict__ y,
                                                       float* __restrict__ out) {
    int g = blockIdx.x * 256 + threadIdx.x;   // 8388608 threads
    int wq = g & 31;                 // output col quad: w0 = 4*wq
    int h  = (g >> 5) & 127;
    int r  = g >> 12;
    int c  = r & 63;
    int tb = r >> 6;

    const float* yp = y + ((size_t)tb * Cn + c) * (HsC * WsC);

    int m = h >> 1;
    int r0, r1; float v0, v1;
    if ((h & 1) == 0) { r0 = (m - 1 < 0) ? 0 : (m - 1); r1 = m; v0 = 0.25f; v1 = 0.75f; }
    else              { r0 = m; r1 = (m + 1 > 63) ? 63 : (m + 1); v0 = 0.75f; v1 = 0.25f; }

    int ca = (2 * wq - 1 < 0) ? 0 : (2 * wq - 1);
    int cb = 2 * wq;
    int cc = 2 * wq + 1;
    int cd = (2 * wq + 2 > 63) ? 63 : (2 * wq + 2);

    const float* ra = yp + r0 * WsC;
    const float* rb = yp + r1 * WsC;
    float a0 = ra[ca], b0 = ra[cb], e0 = ra[cc], d0 = ra[cd];
    float a1 = rb[ca], b1 = rb[cb], e1 = rb[cc], d1 = rb[cd];

    float h00 = 0.25f * a0 + 0.75f * b0;
    float h01 = 0.75f * b0 + 0.25f * e0;
    float h02 = 0.25f * b0 + 0.75f * e0;
    float h03 = 0.75f * e0 + 0.25f * d0;
    float h10 = 0.25f * a1 + 0.75f * b1;
    float h11 = 0.75f * b1 + 0.25f * e1;
    float h12 = 0.25f * b1 + 0.75f * e1;
    float h13 = 0.75f * e1 + 0.25f * d1;

    float4 o;
    o.x = v0 * h00 + v1 * h10;
    o.y = v0 * h01 + v1 * h11;
    o.z = v0 * h02 + v1 * h12;
    o.w = v0 * h03 + v1 * h13;

    *(float4*)(out + ((size_t)tb * Cn + c) * (Hn * Wn) + (size_t)h * Wn + 4 * wq) = o;
}

// ---------------------------------------------------------------------------
extern "C" void kernel_launch(void* const* d_in, const int* in_sizes, int n_in,
                              void* d_out, int out_size, void* d_ws, size_t ws_size,
                              hipStream_t stream) {
    const float* x = (const float*)d_in[0];
    const float* w = (const float*)d_in[1];
    float* out = (float*)d_out;

    uint8_t* sp = (uint8_t*)d_ws;                               // 33554432 B
    float*   y  = (float*)((uint8_t*)d_ws + (size_t)33554432);  // 33554432 B

    lif_kernel<<<2048, 256, 0, stream>>>(x, sp);
    conv_kernel<<<512, 256, 0, stream>>>(sp, w, y);
    upsample_kernel<<<32768, 256, 0, stream>>>(y, out);
}